// Round 7
// baseline (7571.400 us; speedup 1.0000x reference)
//
#include <hip/hip_runtime.h>
#include <hip/hip_bf16.h>

// QLSTM: SEQ=1024, B=64, D_IN=256, D_H=256, fp32 in/out.
// Phase 1: Xp = x @ Wx + bias (MFMA GEMM), epilogue writes D-fragment layout Xp2.
// Phase 2 (NEW): 64 WGs = 4 batch-groups x 16 h-groups; 256 thr (4 waves).
//   r6 lesson: weights-per-CU (512KB) is invariant for any in-CU design ->
//   2483 cyc/step MFMA (M=1 waste) + 2600 cyc DS. Fix: h-split 16-way, M=16 batches.
//   Wave w: ONE 16x16x32 tile-column: cols = {g*256 + hg*16 + w*4 + hl}, tile-col
//   c = hl*4+g -> 8 MFMA/step/wave, weights = 8 uint4 = 32 VGPRs (NO LDS stream).
//   Gates of (b,h) in adjacent lanes -> quad shfl_xor combine (round-3 trick).
//   Cross-WG hx exchange (round-3 redesign): per step each WG publishes 512B
//   (16x 8B relaxed-agent stores) + vmcnt(0) + barrier + ONE release flag store;
//   partners poll 15 flags (15 parallel lanes) then load 7.5KB (L2/LLC-resident).
//   Max skew = 1 step (flag induction) -> 2-slot parity xbuf is race-free.
//   64 WGs <= 256 CUs -> co-resident. Flags monotone in t; prep zeroes per replay.
//   hxA in LDS [2][16 b][256 h] f16 with XOR swizzle (row stride 512B -> bank-flat).

typedef _Float16 f16;
typedef _Float16 f16x2 __attribute__((ext_vector_type(2)));
typedef _Float16 f16x4 __attribute__((ext_vector_type(4)));
typedef _Float16 f16x8 __attribute__((ext_vector_type(8)));
typedef float f32x4 __attribute__((ext_vector_type(4)));
typedef unsigned long long ull;

#define SEQ 1024
#define BATCH 64
#define DIN 256
#define DH 256
#define NCOL 1024

// ---- ws layout (bytes) ----
#define WXP_OFF   0u                 // f16 [32][1024][8]   (xproj B)
#define WHP_OFF   524288u            // f16 [16 hg][4 w][8 kt][64 lane][8]
#define BIAS_OFF  1048576u           // f32 [1024]
#define HXS_OFF   1052672u           // f16 [64][256]
#define CXS_OFF   1085440u           // f32 [64][256]
#define XBUF_OFF  1150976u           // ull [2 par][4 bg][16 hg][4 w][16 b] = 64KB
#define FLAG_OFF  1216512u           // int [64] (+pad to 1KB)
#define XP_OFF    1217536u           // uint2 [Tc][4 bg][16 hg][4 w][64 lane]

__device__ __forceinline__ float fast_sigmoid(float x) {
  float e = __expf(-x);
  return __builtin_amdgcn_rcpf(1.0f + e);
}
__device__ __forceinline__ float fast_tanh(float x) {
  x = fminf(fmaxf(x, -15.0f), 15.0f);
  float e = __expf(2.0f * x);
  return (e - 1.0f) * __builtin_amdgcn_rcpf(e + 1.0f);
}
__device__ __forceinline__ void lds_barrier() {
  asm volatile("s_waitcnt lgkmcnt(0)\n\ts_barrier" ::: "memory");
}
__device__ __forceinline__ f32x4 MF(f16x8 a, f16x8 b, f32x4 c) {
  return __builtin_amdgcn_mfma_f32_16x16x32_f16(a, b, c, 0, 0, 0);
}
#define RB(u) __builtin_bit_cast(f16x8, (u))

// ---------------- prep: convert / repack weights ----------------
__global__ void qlstm_prep(const float* __restrict__ Wf, const float* __restrict__ Wi,
                           const float* __restrict__ Wg, const float* __restrict__ Wo,
                           const float* __restrict__ bf_, const float* __restrict__ bi_,
                           const float* __restrict__ bg_, const float* __restrict__ bo_,
                           f16* __restrict__ Wxp, f16* __restrict__ WhP,
                           float* __restrict__ biasp, int* __restrict__ flags) {
  int tid = blockIdx.x * 256 + threadIdx.x;
  if (tid < 4 * 512 * 256) {
    int g = tid >> 17;
    int rem = tid & 131071;
    int k = rem >> 8, n = rem & 255;
    const float* W = (g == 0) ? Wf : (g == 1) ? Wi : (g == 2) ? Wg : Wo;
    float v = W[k * 256 + n];
    f16 hv = (f16)v;
    if (k < 256) {
      int j = (g << 8) + n;
      Wxp[((size_t)(k >> 3) * 1024 + j) * 8 + (k & 7)] = hv;
    } else {
      int kk = k - 256;                       // hx row 0..255
      int hg = n >> 4, w = (n >> 2) & 3, hl = n & 3;
      int kt = kk >> 5, j = kk & 7;
      int lane = ((kk >> 3) & 3) * 16 + hl * 4 + g;
      WhP[((size_t)((hg * 4 + w) * 8 + kt) * 64 + lane) * 8 + j] = hv;
    }
  }
  if (tid < 1024) {
    int g = tid >> 8, n = tid & 255;
    const float* bb = (g == 0) ? bf_ : (g == 1) ? bi_ : (g == 2) ? bg_ : bo_;
    biasp[tid] = bb[n];
  }
  if (tid < 64) flags[tid] = 0;               // zeroed every launch/replay
}

// ---------------- phase 1: Xp = x @ Wx + bias  (MFMA f16) ----------------
__global__ __launch_bounds__(256) void qlstm_xproj(
    const float* __restrict__ X, const f16* __restrict__ Wxp,
    const float* __restrict__ biasp, uint2* __restrict__ Xp2) {
  __shared__ f16 As[128][72];
  __shared__ f16 Bs[8 * 128 * 8];

  int tid = threadIdx.x;
  int tm = blockIdx.x, tn = blockIdx.y;
  int wave = tid >> 6, lane = tid & 63;
  int qm = (wave & 1) * 64, qn = (wave >> 1) * 64;
  int lm = lane & 15, lk = lane >> 4;

  f32x4 acc[4][4];
#pragma unroll
  for (int a = 0; a < 4; ++a)
#pragma unroll
    for (int b = 0; b < 4; ++b) acc[a][b] = (f32x4)0.0f;

  for (int k0 = 0; k0 < 256; k0 += 64) {
    {
      int r = tid >> 1, c0 = (tid & 1) * 32;
      const float4* src = (const float4*)(X + (size_t)(tm * 128 + r) * 256 + k0 + c0);
#pragma unroll
      for (int i = 0; i < 8; ++i) {
        float4 v = src[i];
        f16x4 pk = {(f16)v.x, (f16)v.y, (f16)v.z, (f16)v.w};
        *(f16x4*)&As[r][c0 + i * 4] = pk;
      }
    }
    {
#pragma unroll
      for (int it = 0; it < 4; ++it) {
        int idx = it * 256 + tid;
        int kgi = idx >> 7, n = idx & 127;
        ((uint4*)Bs)[idx] =
            *(const uint4*)(Wxp + (((size_t)(k0 >> 3) + kgi) * 1024 + tn * 128 + n) * 8);
      }
    }
    __syncthreads();
#pragma unroll
    for (int ks = 0; ks < 2; ++ks) {
      f16x8 af[4], bfr[4];
#pragma unroll
      for (int mi = 0; mi < 4; ++mi)
        af[mi] = *(const f16x8*)&As[qm + mi * 16 + lm][ks * 32 + lk * 8];
#pragma unroll
      for (int ni = 0; ni < 4; ++ni)
        bfr[ni] = *(const f16x8*)&Bs[(((ks * 4 + lk) * 128) + qn + ni * 16 + lm) * 8];
#pragma unroll
      for (int mi = 0; mi < 4; ++mi)
#pragma unroll
        for (int ni = 0; ni < 4; ++ni)
          acc[mi][ni] = __builtin_amdgcn_mfma_f32_16x16x32_f16(af[mi], bfr[ni],
                                                               acc[mi][ni], 0, 0, 0);
    }
    __syncthreads();
  }
  // Epilogue: write D-fragment layout for the seq kernel (one uint2 per (mi,ni)).
  int m0 = tm * 128 + qm, j0 = tn * 128 + qn;
#pragma unroll
  for (int mi = 0; mi < 4; ++mi)
#pragma unroll
    for (int ni = 0; ni < 4; ++ni) {
      int j = j0 + ni * 16 + lm;
      int gg = j >> 8, hh = j & 255;
      int hgx = hh >> 4, wx = (hh >> 2) & 3, hlx = hh & 3;
      int mbase = m0 + mi * 16 + lk * 4;            // 4 consecutive batches
      int tl = mbase >> 6, bb = mbase & 63;
      int bgx = bb >> 4, qx = (bb & 15) >> 2;
      int lane2 = qx * 16 + hlx * 4 + gg;
      float bv = biasp[j];
      f16x2 lo = {(f16)(acc[mi][ni][0] + bv), (f16)(acc[mi][ni][1] + bv)};
      f16x2 hi = {(f16)(acc[mi][ni][2] + bv), (f16)(acc[mi][ni][3] + bv)};
      Xp2[((size_t)((tl * 4 + bgx) * 16 + hgx) * 4 + wx) * 64 + lane2] =
          uint2{__builtin_bit_cast(unsigned, lo), __builtin_bit_cast(unsigned, hi)};
    }
}

// ---------------- phase 2: h-split LSTM, M=16 MFMA, cross-WG exchange ----------------
__global__ __launch_bounds__(256) void qlstm_seq(
    const uint2* __restrict__ Xp2, const uint4* __restrict__ WhP,
    float* __restrict__ out, f16* __restrict__ hxs, float* __restrict__ cxs,
    float* __restrict__ hxout, float* __restrict__ cxout,
    ull* __restrict__ xbuf, int* __restrict__ flags, int t0, int t1) {
  __shared__ f16 hxA[2][16][256];                 // swizzled: byte ^= (b&7)<<4

  int tid = threadIdx.x;
  int w = tid >> 6, lane = tid & 63;
  int bid = blockIdx.x, bg = bid & 3, hg = bid >> 2;
  int c = lane & 15, q = lane >> 4, hl = c >> 2, g = c & 3;
  int bq = q * 4;                                  // batch rows r=0..3
  int h = hg * 16 + w * 4 + hl;                    // my h column

  // weights: 8 tiles fully register-resident
  uint4 wr[8];
  {
    const uint4* wp = WhP + (size_t)((hg * 4 + w) * 8) * 64 + lane;
#pragma unroll
    for (int kt = 0; kt < 8; ++kt) wr[kt] = wp[kt * 64];
  }

  // prologue: stage hxA[par0] (full 16b x 256h, swizzled)
  int par0 = t0 & 1;
  {
    char* dst = (char*)&hxA[par0][0][0];
#pragma unroll
    for (int uu = 0; uu < 2; ++uu) {
      int u = tid + uu * 256;
      int b = u >> 5, off = (u & 31) * 16;
      uint4 v;
      if (t0 == 0) v = uint4{0u, 0u, 0u, 0u};
      else v = *(const uint4*)((const char*)hxs + (size_t)(bg * 16 + b) * 512 + off);
      *(uint4*)(dst + b * 512 + (off ^ ((b & 7) << 4))) = v;
    }
  }
  f32x4 cx = {0.f, 0.f, 0.f, 0.f};
  if (t0 != 0) {
#pragma unroll
    for (int r = 0; r < 4; ++r) cx[r] = cxs[(size_t)(bg * 16 + bq + r) * 256 + h];
  }
  int pidx = 0;
  if (lane < 15) { int hp = lane + (lane >= hg ? 1 : 0); pidx = bg * 16 + hp; }

  __syncthreads();

  f32x4 hvv = {0.f, 0.f, 0.f, 0.f};
  for (int t = t0; t < t1; ++t) {
    int par = t & 1, parn = par ^ 1;
    const char* ap = (const char*)&hxA[par][0][0];
    int b15 = lane & 15, sw = (b15 & 7) << 4, koff = (lane >> 4) << 4;

    // Xp for this step: one coalesced 8B load in D-fragment layout
    uint2 xpv = Xp2[((size_t)((t - t0) * 4 + bg) * 16 + hg) * 64 * 4 + w * 64 + lane];

    // 8 K-tiles of MFMA, dual accs, A pipelined 1 ahead
#define ARD2(kt) (*(const f16x8*)(ap + b15 * 512 + (((kt) * 64 + koff) ^ sw)))
    f32x4 qe = {0.f, 0.f, 0.f, 0.f}, qo = {0.f, 0.f, 0.f, 0.f};
    f16x8 A0 = ARD2(0), A1 = ARD2(1);
    qe = MF(A0, RB(wr[0]), qe); A0 = ARD2(2);
    qo = MF(A1, RB(wr[1]), qo); A1 = ARD2(3);
    qe = MF(A0, RB(wr[2]), qe); A0 = ARD2(4);
    qo = MF(A1, RB(wr[3]), qo); A1 = ARD2(5);
    qe = MF(A0, RB(wr[4]), qe); A0 = ARD2(6);
    qo = MF(A1, RB(wr[5]), qo); A1 = ARD2(7);
    qe = MF(A0, RB(wr[6]), qe);
    qo = MF(A1, RB(wr[7]), qo);
#undef ARD2

    f16x2 xlo = __builtin_bit_cast(f16x2, xpv.x);
    f16x2 xhi = __builtin_bit_cast(f16x2, xpv.y);
    f32x4 p;
    p[0] = qe[0] + qo[0] + (float)xlo[0];
    p[1] = qe[1] + qo[1] + (float)xlo[1];
    p[2] = qe[2] + qo[2] + (float)xhi[0];
    p[3] = qe[3] + qo[3] + (float)xhi[1];

    // quad gate combine: lanes c = hl*4 + g, g in {f,i,g,o}
    f32x4 p1, p2, p3;
#pragma unroll
    for (int r = 0; r < 4; ++r) {
      p1[r] = __shfl_xor(p[r], 1, 64);
      p2[r] = __shfl_xor(p[r], 2, 64);
      p3[r] = __shfl_xor(p1[r], 2, 64);
    }
    f32x4 vF = (g == 0) ? p : (g == 1) ? p1 : (g == 2) ? p2 : p3;
    f32x4 vI = (g == 1) ? p : (g == 0) ? p1 : (g == 3) ? p2 : p3;
    f32x4 vG = (g == 2) ? p : (g == 3) ? p1 : (g == 0) ? p2 : p3;
    f32x4 vO = (g == 3) ? p : (g == 2) ? p1 : (g == 1) ? p2 : p3;

#pragma unroll
    for (int r = 0; r < 4; ++r) {
      float f_ = fast_sigmoid(vF[r]);
      float i_ = fast_sigmoid(vI[r]);
      float g_ = fast_tanh(vG[r]);
      float o_ = fast_sigmoid(vO[r]);
      cx[r] = fmaf(f_, cx[r], i_ * g_);
      hvv[r] = o_ * fast_tanh(cx[r]);
    }

    // 4x4 butterfly transpose among lanes {q*16 + j*4 + g}: z[j] = hv(b=bq+hl, h-local j)
    f32x4 y, z;
    {
      float ty0 = __shfl_xor(hvv[1], 4, 64), ty1 = __shfl_xor(hvv[0], 4, 64);
      float ty2 = __shfl_xor(hvv[3], 4, 64), ty3 = __shfl_xor(hvv[2], 4, 64);
      bool e0 = (hl & 1) == 0;
      y[0] = e0 ? hvv[0] : ty0; y[1] = e0 ? ty1 : hvv[1];
      y[2] = e0 ? hvv[2] : ty2; y[3] = e0 ? ty3 : hvv[3];
      float tz0 = __shfl_xor(y[2], 8, 64), tz1 = __shfl_xor(y[3], 8, 64);
      float tz2 = __shfl_xor(y[0], 8, 64), tz3 = __shfl_xor(y[1], 8, 64);
      bool e1 = ((hl >> 1) & 1) == 0;
      z[0] = e1 ? y[0] : tz0; z[1] = e1 ? y[1] : tz1;
      z[2] = e1 ? tz2 : y[2]; z[3] = e1 ? tz3 : y[3];
    }

    // publish: own LDS slot + 8B agent store to xbuf (g==0 lanes, b = bq+hl)
    if (g == 0) {
      int b = bq + hl;
      f16x4 zz = {(f16)z[0], (f16)z[1], (f16)z[2], (f16)z[3]};
      ull pk = __builtin_bit_cast(ull, zz);
      *(ull*)(((char*)&hxA[parn][0][0]) + b * 512 + ((hg * 32 + w * 8) ^ ((b & 7) << 4))) = pk;
      __hip_atomic_store(&xbuf[((size_t)(parn * 4 + bg) * 16 + hg) * 64 + w * 16 + b],
                         pk, __ATOMIC_RELAXED, __HIP_MEMORY_SCOPE_AGENT);
    }
    asm volatile("s_waitcnt vmcnt(0)" ::: "memory");   // xbuf at coherence point
    __builtin_amdgcn_s_barrier();                      // all waves' stores done
    if (tid == 0)
      __hip_atomic_store(&flags[bg * 16 + hg], t + 1, __ATOMIC_RELEASE,
                         __HIP_MEMORY_SCOPE_AGENT);

    // out stores ride during the poll window (never drained in-loop)
    if (g == 0) {
      float* op = out + ((size_t)t * BATCH + bg * 16 + bq) * 256 + h;
      op[0] = hvv[0]; op[256] = hvv[1]; op[512] = hvv[2]; op[768] = hvv[3];
    }

    if (t + 1 < t1) {
      // poll 15 partner flags (15 parallel lanes)
      if (lane < 15) {
        while (__hip_atomic_load(&flags[pidx], __ATOMIC_ACQUIRE,
                                 __HIP_MEMORY_SCOPE_AGENT) < t + 1)
          __builtin_amdgcn_s_sleep(1);
      }
      // stage 15 partner blocks (960 x 8B) into hxA[parn]
      const ull* src = xbuf + (size_t)(parn * 4 + bg) * 1024;
      char* dst = (char*)&hxA[parn][0][0];
#pragma unroll
      for (int k2 = 0; k2 < 4; ++k2) {
        int u = tid + k2 * 256;
        if (u < 960) {
          int pp = u >> 6, rem = u & 63, wp2 = rem >> 4, b = rem & 15;
          int hgp = pp + (pp >= hg ? 1 : 0);
          ull v = __hip_atomic_load(src + hgp * 64 + wp2 * 16 + b,
                                    __ATOMIC_RELAXED, __HIP_MEMORY_SCOPE_AGENT);
          *(ull*)(dst + b * 512 + ((hgp * 32 + wp2 * 8) ^ ((b & 7) << 4))) = v;
        }
      }
      lds_barrier();                                   // stage + own writes visible
    }
  }

  if (g == 0) {
#pragma unroll
    for (int r = 0; r < 4; ++r) {
      int B = bg * 16 + bq + r;
      hxs[(size_t)B * 256 + h] = (f16)hvv[r];
      cxs[(size_t)B * 256 + h] = cx[r];
      if (t1 == SEQ) {
        hxout[(size_t)B * 256 + h] = hvv[r];
        cxout[(size_t)B * 256 + h] = cx[r];
      }
    }
  }
}

extern "C" void kernel_launch(void* const* d_in, const int* in_sizes, int n_in,
                              void* d_out, int out_size, void* d_ws, size_t ws_size,
                              hipStream_t stream) {
  const float* X  = (const float*)d_in[0];
  const float* Wf = (const float*)d_in[1]; const float* bf_ = (const float*)d_in[2];
  const float* Wi = (const float*)d_in[3]; const float* bi_ = (const float*)d_in[4];
  const float* Wg = (const float*)d_in[5]; const float* bg_ = (const float*)d_in[6];
  const float* Wo = (const float*)d_in[7]; const float* bo_ = (const float*)d_in[8];
  float* out = (float*)d_out;

  char* ws = (char*)d_ws;
  f16*   Wxp   = (f16*)(ws + WXP_OFF);
  f16*   WhP   = (f16*)(ws + WHP_OFF);
  float* biasp = (float*)(ws + BIAS_OFF);
  f16*   hxs   = (f16*)(ws + HXS_OFF);
  float* cxs   = (float*)(ws + CXS_OFF);
  ull*   xbuf  = (ull*)(ws + XBUF_OFF);
  int*   flags = (int*)(ws + FLAG_OFF);
  uint2* Xp2   = (uint2*)(ws + XP_OFF);

  size_t avail = (ws_size > XP_OFF) ? (ws_size - XP_OFF) : 0;
  int Tc = SEQ;
  while (Tc > 2 && (size_t)Tc * BATCH * NCOL * 2 > avail) Tc >>= 1;

  qlstm_prep<<<2048, 256, 0, stream>>>(Wf, Wi, Wg, Wo, bf_, bi_, bg_, bo_,
                                       Wxp, WhP, biasp, flags);

  float* hxout = out + (size_t)SEQ * BATCH * DH;
  float* cxout = hxout + BATCH * DH;

  for (int t0 = 0; t0 < SEQ; t0 += Tc) {
    dim3 g1(Tc * BATCH / 128, NCOL / 128);
    qlstm_xproj<<<g1, 256, 0, stream>>>(X + (size_t)t0 * BATCH * DIN, Wxp, biasp, Xp2);
    qlstm_seq<<<64, 256, 0, stream>>>(Xp2, (const uint4*)WhP, out, hxs, cxs,
                                      hxout, cxout, xbuf, flags, t0, t0 + Tc);
  }
}

// Round 8
// 1317.310 us; speedup vs baseline: 5.7476x; 5.7476x over previous
//
#include <hip/hip_runtime.h>
#include <hip/hip_bf16.h>

// QLSTM: SEQ=1024, B=64, D_IN=256, D_H=256, fp32 in/out.
// Phase 1: Xp = x @ Wx + bias (f16 MFMA GEMM) — unchanged, f16 precision.
// Phase 2: 64 WGs (1/batch), 512 thr, 8 waves, 2/SIMD, ONE lds_barrier/step.
//   r3/r7 lesson: cross-CU per-step exchange costs 5-7us/step (L2 RTT) — dead.
//   r6 lesson: in-CU, ALL of Wh must flow through MFMA B-port every step.
//     f16: 512KB @ ~211 B/cyc = 2480 cyc/step floor + 2600 cyc LDS stream.
//   THIS ROUND: i8 weights halve the bytes. mfma_i32_16x16x64_i8: 256 tiles/CU/step
//     ~ 1300 cyc, and 32 tiles/wave = 128 VGPRs -> Wh FULLY register-resident:
//     the LDS weight stream is GONE. DS/step = 4 A-reads + 1 packed b64 write /wave.
//   Precision engineering: per-COLUMN scales s_j = max|W:,j|/127 (dw <= 1.7e-4),
//     exact i32 accumulate, hx as i8 @ scale 127 (dh <= 1/254 dominant),
//     x-projection stays f16. Est. added absmax ~2-4e-3.
//   k-permutation pi (same perm on A rows and B rows -> contraction invariant):
//     pi(p) -> h = 32(p>>5) + ((p&31)>>1) + 16(p&1), so lane c's two hv bytes
//     (h0=32w+c, h1=h0+16) are ADJACENT -> 2 shfl_xor pack -> one b64/4 lanes.
//   M=1 (rows 1-15 garbage, never read; uniform A-read broadcasts row 0's hx).

typedef _Float16 f16;
typedef _Float16 f16x4 __attribute__((ext_vector_type(4)));
typedef _Float16 f16x8 __attribute__((ext_vector_type(8)));
typedef float f32x4 __attribute__((ext_vector_type(4)));
typedef int i32x4 __attribute__((ext_vector_type(4)));

#define SEQ 1024
#define BATCH 64
#define DIN 256
#define DH 256
#define NCOL 1024

// ---- ws layout (bytes) ----
#define WXP_OFF   0u                 // f16 [32][1024][8]            = 524288
#define WHQ_OFF   524288u            // i8 tiles [8 w][8 nt][4 kt][64 lane][16] = 262144
#define SCL_OFF   786432u            // f32 [1024] per-col scale/127 = 4096
#define BIAS_OFF  790528u            // f32 [1024]                   = 4096
#define HXS8_OFF  794624u            // i8  [64][256] permuted state = 16384
#define CXS_OFF   811008u            // f32 [64][256]                = 65536
#define XP_OFF    876544u            // f16 [Tc*64][1024]

__device__ __forceinline__ float fast_sigmoid(float x) {
  float e = __expf(-x);
  return __builtin_amdgcn_rcpf(1.0f + e);
}
__device__ __forceinline__ float fast_tanh(float x) {
  x = fminf(fmaxf(x, -15.0f), 15.0f);
  float e = __expf(2.0f * x);
  return (e - 1.0f) * __builtin_amdgcn_rcpf(e + 1.0f);
}
// LDS-only barrier: no vmcnt drain (out-stores / Xp loads ride across).
__device__ __forceinline__ void lds_barrier() {
  asm volatile("s_waitcnt lgkmcnt(0)\n\ts_barrier" ::: "memory");
}

// ---------------- prep A: Wxp (f16 for xproj) + bias ----------------
__global__ void qlstm_prep(const float* __restrict__ Wf, const float* __restrict__ Wi,
                           const float* __restrict__ Wg, const float* __restrict__ Wo,
                           const float* __restrict__ bf_, const float* __restrict__ bi_,
                           const float* __restrict__ bg_, const float* __restrict__ bo_,
                           f16* __restrict__ Wxp, float* __restrict__ biasp) {
  int tid = blockIdx.x * 256 + threadIdx.x;
  if (tid < 4 * 256 * 256) {
    int g = tid >> 16;
    int rem = tid & 65535;
    int k = rem >> 8, n = rem & 255;           // k < 256: x-rows only
    const float* W = (g == 0) ? Wf : (g == 1) ? Wi : (g == 2) ? Wg : Wo;
    float v = W[k * 256 + n];
    int j = (g << 8) + n;
    Wxp[((size_t)(k >> 3) * 1024 + j) * 8 + (k & 7)] = (f16)v;
  }
  if (tid < 1024) {
    int g = tid >> 8, n = tid & 255;
    const float* bb = (g == 0) ? bf_ : (g == 1) ? bi_ : (g == 2) ? bg_ : bo_;
    biasp[tid] = bb[n];
  }
}

// ---------------- prep B: per-column i8 quantization of Wh ----------------
__global__ __launch_bounds__(256) void qlstm_prepq(
    const float* __restrict__ Wf, const float* __restrict__ Wi,
    const float* __restrict__ Wg, const float* __restrict__ Wo,
    char* __restrict__ WhQ, float* __restrict__ scl) {
  int j = blockIdx.x * 256 + threadIdx.x;     // 0..1023 gate-column
  if (j >= 1024) return;
  int g = j >> 8, n = j & 255;
  const float* W = (g == 0) ? Wf : (g == 1) ? Wi : (g == 2) ? Wg : Wo;
  float mx = 0.0f;
  for (int r = 0; r < 256; ++r) mx = fmaxf(mx, fabsf(W[(256 + r) * 256 + n]));
  float s = (mx > 0.0f) ? mx * (1.0f / 127.0f) : 1.0f;
  float inv = 1.0f / s;
  int w = n >> 5, sh = (n >> 4) & 1, c = n & 15, nt = g * 2 + sh;
  size_t tb = ((size_t)(w * 8 + nt) * 4) * 1024;      // 4 kt tiles x 1024 B
  for (int kp = 0; kp < 256; ++kp) {
    int r = 32 * (kp >> 5) + ((kp & 31) >> 1) + 16 * (kp & 1);   // pi(kp)
    float v = W[(256 + r) * 256 + n];
    int q = (int)rintf(v * inv);
    q = q > 127 ? 127 : (q < -127 ? -127 : q);
    int kt = kp >> 6, lane = ((kp >> 4) & 3) * 16 + c, jj = kp & 15;
    WhQ[tb + (size_t)kt * 1024 + lane * 16 + jj] = (char)q;
  }
  scl[j] = s * (1.0f / 127.0f);               // final scale: s_j/127
}

// ---------------- phase 1: Xp = x @ Wx + bias  (MFMA f16) ----------------
__global__ __launch_bounds__(256) void qlstm_xproj(
    const float* __restrict__ X, const f16* __restrict__ Wxp,
    const float* __restrict__ biasp, f16* __restrict__ Xp) {
  __shared__ f16 As[128][72];
  __shared__ f16 Bs[8 * 128 * 8];

  int tid = threadIdx.x;
  int tm = blockIdx.x, tn = blockIdx.y;
  int wave = tid >> 6, lane = tid & 63;
  int qm = (wave & 1) * 64, qn = (wave >> 1) * 64;
  int lm = lane & 15, lk = lane >> 4;

  f32x4 acc[4][4];
#pragma unroll
  for (int a = 0; a < 4; ++a)
#pragma unroll
    for (int b = 0; b < 4; ++b) acc[a][b] = (f32x4)0.0f;

  for (int k0 = 0; k0 < 256; k0 += 64) {
    {
      int r = tid >> 1, c0 = (tid & 1) * 32;
      const float4* src = (const float4*)(X + (size_t)(tm * 128 + r) * 256 + k0 + c0);
#pragma unroll
      for (int i = 0; i < 8; ++i) {
        float4 v = src[i];
        f16x4 pk = {(f16)v.x, (f16)v.y, (f16)v.z, (f16)v.w};
        *(f16x4*)&As[r][c0 + i * 4] = pk;
      }
    }
    {
#pragma unroll
      for (int it = 0; it < 4; ++it) {
        int idx = it * 256 + tid;
        int kgi = idx >> 7, n = idx & 127;
        ((uint4*)Bs)[idx] =
            *(const uint4*)(Wxp + (((size_t)(k0 >> 3) + kgi) * 1024 + tn * 128 + n) * 8);
      }
    }
    __syncthreads();
#pragma unroll
    for (int ks = 0; ks < 2; ++ks) {
      f16x8 af[4], bfr[4];
#pragma unroll
      for (int mi = 0; mi < 4; ++mi)
        af[mi] = *(const f16x8*)&As[qm + mi * 16 + lm][ks * 32 + lk * 8];
#pragma unroll
      for (int ni = 0; ni < 4; ++ni)
        bfr[ni] = *(const f16x8*)&Bs[(((ks * 4 + lk) * 128) + qn + ni * 16 + lm) * 8];
#pragma unroll
      for (int mi = 0; mi < 4; ++mi)
#pragma unroll
        for (int ni = 0; ni < 4; ++ni)
          acc[mi][ni] = __builtin_amdgcn_mfma_f32_16x16x32_f16(af[mi], bfr[ni],
                                                               acc[mi][ni], 0, 0, 0);
    }
    __syncthreads();
  }
  int m0 = tm * 128 + qm, j0 = tn * 128 + qn;
#pragma unroll
  for (int mi = 0; mi < 4; ++mi)
#pragma unroll
    for (int ni = 0; ni < 4; ++ni) {
      int j = j0 + ni * 16 + lm;
      float bv = biasp[j];
#pragma unroll
      for (int r = 0; r < 4; ++r) {
        int m = m0 + mi * 16 + lk * 4 + r;
        Xp[(size_t)m * 1024 + j] = (f16)(acc[mi][ni][r] + bv);
      }
    }
}

// ---------------- phase 2: sequential LSTM, i8 MFMA, full residency ----------------
__device__ __forceinline__ i32x4 MQ(i32x4 a, i32x4 b, i32x4 c) {
  return __builtin_amdgcn_mfma_i32_16x16x64_i8(a, b, c, 0, 0, 0);
}

__global__ __launch_bounds__(512)
__attribute__((amdgpu_waves_per_eu(2, 2))) void qlstm_seq(
    const f16* __restrict__ Xp, const i32x4* __restrict__ WhQ,
    const float* __restrict__ scl,
    float* __restrict__ out, char* __restrict__ hxs8, float* __restrict__ cxs,
    float* __restrict__ hxout, float* __restrict__ cxout, int t0, int t1) {
  __shared__ char hxq[2][256];                 // pi-permuted i8 hidden state

  int tid = threadIdx.x;
  int w = tid >> 6, lane = tid & 63, c = lane & 15;
  int b = blockIdx.x;
  int h0 = w * 32 + c, h1 = h0 + 16;

  // Wh fully register-resident: 8 nt x 4 kt tiles, 16B/lane each = 128 regs
  i32x4 wq[8][4];
  {
    const i32x4* wp = WhQ + (size_t)w * 32 * 64 + lane;
#pragma unroll
    for (int nt = 0; nt < 8; ++nt)
#pragma unroll
      for (int kt = 0; kt < 4; ++kt) wq[nt][kt] = wp[(nt * 4 + kt) * 64];
  }
  // per-column final scales (s_j/127) for my 8 acc columns
  float sc[8];
#pragma unroll
  for (int nt = 0; nt < 8; ++nt)
    sc[nt] = scl[(nt >> 1) * 256 + w * 32 + (nt & 1) * 16 + c];

  int par0 = t0 & 1;
  if (tid < 16) {
    uint4 v;
    if (t0 == 0) v = uint4{0u, 0u, 0u, 0u};
    else v = ((const uint4*)(hxs8 + (size_t)b * 256))[tid];
    *(uint4*)(&hxq[par0][tid * 16]) = v;
  }
  float cx0 = 0.0f, cx1 = 0.0f;
  if (t0 != 0) { cx0 = cxs[(size_t)b * 256 + h0]; cx1 = cxs[(size_t)b * 256 + h1]; }

  __syncthreads();

  int koff = (lane >> 4) << 4;                 // A-frag k-chunk byte offset
  float hv0 = 0.0f, hv1 = 0.0f;
  for (int t = t0; t < t1; ++t) {
    int par = t & 1, parn = par ^ 1;
    const char* hp = &hxq[par][0];

    // Xp for this step: 8 scalar f16 loads (ride vmcnt; consumed at tail)
    const f16* xq = Xp + ((size_t)(t - t0) * BATCH + b) * NCOL;
    f16 xv[8];
#pragma unroll
    for (int nt = 0; nt < 8; ++nt)
      xv[nt] = xq[(nt >> 1) * 256 + w * 32 + (nt & 1) * 16 + c];

    // 4 K-tiles x 8 N-tiles of i8 MFMA; A pipelined one ahead
    i32x4 acc[8];
#pragma unroll
    for (int nt = 0; nt < 8; ++nt) acc[nt] = i32x4{0, 0, 0, 0};
    i32x4 a0 = *(const i32x4*)(hp + 0 * 64 + koff);
    i32x4 a1 = *(const i32x4*)(hp + 1 * 64 + koff);
#pragma unroll
    for (int nt = 0; nt < 8; ++nt) acc[nt] = MQ(a0, wq[nt][0], acc[nt]);
    a0 = *(const i32x4*)(hp + 2 * 64 + koff);
#pragma unroll
    for (int nt = 0; nt < 8; ++nt) acc[nt] = MQ(a1, wq[nt][1], acc[nt]);
    a1 = *(const i32x4*)(hp + 3 * 64 + koff);
#pragma unroll
    for (int nt = 0; nt < 8; ++nt) acc[nt] = MQ(a0, wq[nt][2], acc[nt]);
#pragma unroll
    for (int nt = 0; nt < 8; ++nt) acc[nt] = MQ(a1, wq[nt][3], acc[nt]);

    // D row 0 (lanes 0-15, reg 0) -> pre-activations; dequant + add x-proj
    float p[8];
#pragma unroll
    for (int nt = 0; nt < 8; ++nt)
      p[nt] = fmaf((float)acc[nt][0], sc[nt], (float)xv[nt]);

    // nt = g*2+s: s=0 -> h0 gates {f,i,g,o} = p[0,2,4,6]; s=1 -> h1 = p[1,3,5,7]
    float vf0 = fast_sigmoid(p[0]), vf1 = fast_sigmoid(p[1]);
    float vi0 = fast_sigmoid(p[2]), vi1 = fast_sigmoid(p[3]);
    float vg0 = fast_tanh(p[4]),    vg1 = fast_tanh(p[5]);
    float vo0 = fast_sigmoid(p[6]), vo1 = fast_sigmoid(p[7]);
    cx0 = fmaf(vf0, cx0, vi0 * vg0); hv0 = vo0 * fast_tanh(cx0);
    cx1 = fmaf(vf1, cx1, vi1 * vg1); hv1 = vo1 * fast_tanh(cx1);

    if (lane < 16) {
      float* op = out + ((size_t)t * BATCH + b) * 256;
      op[h0] = hv0; op[h1] = hv1;              // rides vmcnt across barrier
    }

    // quantize hv -> i8, pack 2 bytes/lane -> b64 per 4 lanes (pi layout)
    int q0 = (int)rintf(hv0 * 127.0f);
    int q1 = (int)rintf(hv1 * 127.0f);
    unsigned v16 = (unsigned)(q0 & 0xff) | ((unsigned)(q1 & 0xff) << 8);
    unsigned px = (unsigned)__shfl_xor((int)v16, 1, 64);
    unsigned v32 = v16 | (px << 16);           // valid at even lanes
    unsigned py = (unsigned)__shfl_xor((int)v32, 2, 64);
    if (lane < 16 && (lane & 3) == 0)
      *(uint2*)(&hxq[parn][w * 32 + (lane >> 2) * 8]) = uint2{v32, py};

    lds_barrier();                             // lgkmcnt(0)+s_barrier only
  }

  // persist state across chunk launches (exact i8 state + f32 cx)
  if (tid < 16)
    ((uint4*)(hxs8 + (size_t)b * 256))[tid] = *(const uint4*)(&hxq[t1 & 1][tid * 16]);
  if (lane < 16) {
    cxs[(size_t)b * 256 + h0] = cx0; cxs[(size_t)b * 256 + h1] = cx1;
    if (t1 == SEQ) {
      hxout[(size_t)b * 256 + h0] = hv0; hxout[(size_t)b * 256 + h1] = hv1;
      cxout[(size_t)b * 256 + h0] = cx0; cxout[(size_t)b * 256 + h1] = cx1;
    }
  }
}

extern "C" void kernel_launch(void* const* d_in, const int* in_sizes, int n_in,
                              void* d_out, int out_size, void* d_ws, size_t ws_size,
                              hipStream_t stream) {
  const float* X  = (const float*)d_in[0];
  const float* Wf = (const float*)d_in[1]; const float* bf_ = (const float*)d_in[2];
  const float* Wi = (const float*)d_in[3]; const float* bi_ = (const float*)d_in[4];
  const float* Wg = (const float*)d_in[5]; const float* bg_ = (const float*)d_in[6];
  const float* Wo = (const float*)d_in[7]; const float* bo_ = (const float*)d_in[8];
  float* out = (float*)d_out;

  char* ws = (char*)d_ws;
  f16*   Wxp   = (f16*)(ws + WXP_OFF);
  char*  WhQ   = (char*)(ws + WHQ_OFF);
  float* scl   = (float*)(ws + SCL_OFF);
  float* biasp = (float*)(ws + BIAS_OFF);
  char*  hxs8  = (char*)(ws + HXS8_OFF);
  float* cxs   = (float*)(ws + CXS_OFF);
  f16*   Xp    = (f16*)(ws + XP_OFF);

  size_t avail = (ws_size > XP_OFF) ? (ws_size - XP_OFF) : 0;
  int Tc = SEQ;
  while (Tc > 2 && (size_t)Tc * BATCH * NCOL * 2 > avail) Tc >>= 1;

  qlstm_prep<<<1024, 256, 0, stream>>>(Wf, Wi, Wg, Wo, bf_, bi_, bg_, bo_,
                                       Wxp, biasp);
  qlstm_prepq<<<4, 256, 0, stream>>>(Wf, Wi, Wg, Wo, WhQ, scl);

  float* hxout = out + (size_t)SEQ * BATCH * DH;
  float* cxout = hxout + BATCH * DH;

  for (int t0 = 0; t0 < SEQ; t0 += Tc) {
    dim3 g1(Tc * BATCH / 128, NCOL / 128);
    qlstm_xproj<<<g1, 256, 0, stream>>>(X + (size_t)t0 * BATCH * DIN, Wxp, biasp, Xp);
    qlstm_seq<<<BATCH, 512, 0, stream>>>(Xp, (const i32x4*)WhQ, scl, out, hxs8, cxs,
                                         hxout, cxout, t0, t0 + Tc);
  }
}